// Round 8
// baseline (143.221 us; speedup 1.0000x reference)
//
#include <hip/hip_runtime.h>

#define N_NODES 50000
#define N_EDGES 800000
#define N_FEAT  128
#define N_HID   64

#define BKT_LOG 9
#define BKT_SZ  512                                  // nodes per bucket
#define NBKT    ((N_NODES + BKT_SZ - 1) / BKT_SZ)    // 98
#define CH      4096                                 // edges per partition block
#define NB1     ((N_EDGES + CH - 1) / CH)            // 196

__device__ inline void fma4(float4& acc, float s, const float4& w) {
    acc.x = fmaf(s, w.x, acc.x);
    acc.y = fmaf(s, w.y, acc.y);
    acc.z = fmaf(s, w.z, acc.z);
    acc.w = fmaf(s, w.w, acc.w);
}

__device__ inline unsigned short f2bf(float f) {          // RNE f32 -> bf16
    unsigned u = __float_as_uint(f);
    u = u + 0x7FFFu + ((u >> 16) & 1u);
    return (unsigned short)(u >> 16);
}
__device__ inline float bf2f(unsigned short v) { return __uint_as_float(((unsigned)v) << 16); }

// ---------- tiled GEMM: o[row][col] = sum_k a[row*K+k] * w[k*64+col], bf16 out ----------
template <int K>
__global__ __launch_bounds__(256) void gemm_tile(const float* __restrict__ a,
                                                 const float* __restrict__ w,
                                                 unsigned short* __restrict__ o) {
    __shared__ float lw[K * N_HID];
    int tid = threadIdx.x;
    for (int idx = tid * 4; idx < K * N_HID; idx += 256 * 4)
        *(float4*)&lw[idx] = *(const float4*)&w[idx];
    __syncthreads();

    int row0 = blockIdx.x * 32 + (tid >> 4) * 2;
    if (row0 >= N_NODES) return;
    bool two = (row0 + 1) < N_NODES;
    int c4 = (tid & 15) * 4;

    const float* a0 = a + (long)row0 * K;
    const float* a1 = two ? (a0 + K) : a0;

    float4 acc0 = make_float4(0.f, 0.f, 0.f, 0.f);
    float4 acc1 = acc0;

#pragma unroll 8
    for (int k4 = 0; k4 < K / 4; ++k4) {
        float4 xa = *(const float4*)(a0 + k4 * 4);
        float4 xb = *(const float4*)(a1 + k4 * 4);
        const float* wk = &lw[(k4 * 4) * N_HID + c4];
        float4 w0 = *(const float4*)(wk);
        float4 w1 = *(const float4*)(wk + N_HID);
        float4 w2 = *(const float4*)(wk + 2 * N_HID);
        float4 w3 = *(const float4*)(wk + 3 * N_HID);
        fma4(acc0, xa.x, w0); fma4(acc1, xb.x, w0);
        fma4(acc0, xa.y, w1); fma4(acc1, xb.y, w1);
        fma4(acc0, xa.z, w2); fma4(acc1, xb.z, w2);
        fma4(acc0, xa.w, w3); fma4(acc1, xb.w, w3);
    }

    unsigned short* op = o + (long)row0 * N_HID + c4;
    *(ushort4*)op = make_ushort4(f2bf(acc0.x), f2bf(acc0.y), f2bf(acc0.z), f2bf(acc0.w));
    if (two)
        *(ushort4*)(op + N_HID) = make_ushort4(f2bf(acc1.x), f2bf(acc1.y), f2bf(acc1.z), f2bf(acc1.w));
}

// ---------- CSR build: decoupled radix partition (NO global atomics) ----------
__global__ __launch_bounds__(256) void binhist(const int* __restrict__ dst,
                                               int* __restrict__ cnt,
                                               int* __restrict__ cnt_t) {
    __shared__ int h[NBKT];
    int t = threadIdx.x;
    if (t < NBKT) h[t] = 0;
    __syncthreads();
    int e0 = blockIdx.x * CH;
    for (int i = t; i < CH; i += 256) {
        int e = e0 + i;
        if (e < N_EDGES) atomicAdd(&h[dst[e] >> BKT_LOG], 1);
    }
    __syncthreads();
    if (t < NBKT) {
        int v = h[t];
        cnt[blockIdx.x * NBKT + t] = v;
        cnt_t[t * NB1 + blockIdx.x] = v;
    }
}

__global__ __launch_bounds__(128) void binscan(const int* __restrict__ cnt_t,
                                               int* __restrict__ off,
                                               int* __restrict__ bstart) {
    __shared__ int tot[128];
    int t = threadIdx.x;
    int s = 0;
    if (t < NBKT) {
        const int4* p = (const int4*)(cnt_t + t * NB1);   // NB1 % 4 == 0
#pragma unroll 7
        for (int q = 0; q < NB1 / 4; ++q) {
            int4 v = p[q];
            s += v.x + v.y + v.z + v.w;
        }
    }
    tot[t] = s;
    __syncthreads();
    for (int o = 1; o < 128; o <<= 1) {
        int u = (t >= o) ? tot[t - o] : 0;
        __syncthreads();
        tot[t] += u;
        __syncthreads();
    }
    int excl = tot[t] - s;
    if (t < NBKT) {
        bstart[t] = excl;
        int run = excl;
        const int* p = cnt_t + t * NB1;
        for (int bdx = 0; bdx < NB1; ++bdx) {
            off[bdx * NBKT + t] = run;
            run += p[bdx];
        }
        if (t == NBKT - 1) bstart[NBKT] = run;   // == N_EDGES
    }
}

__global__ __launch_bounds__(256) void binscatter(const int* __restrict__ src,
                                                  const int* __restrict__ dst,
                                                  const float* __restrict__ ew,
                                                  const int* __restrict__ off,
                                                  uint2* __restrict__ slab) {
    __shared__ int cur[NBKT];
    int t = threadIdx.x;
    if (t < NBKT) cur[t] = off[blockIdx.x * NBKT + t];
    __syncthreads();
    int e0 = blockIdx.x * CH;
    for (int i = t; i < CH; i += 256) {
        int e = e0 + i;
        if (e >= N_EDGES) continue;
        int d = dst[e];
        int bin = d >> BKT_LOG;
        int p = atomicAdd(&cur[bin], 1);
        slab[p] = make_uint2((unsigned)src[e] | ((unsigned)(d & (BKT_SZ - 1)) << 16),
                             __float_as_uint(ew[e]));
    }
}

// phase 4: per-bucket LDS counting sort -> packed 4B edges {src:16 | bf16(w):16} + start[]
__global__ __launch_bounds__(512) void sort_bucket(const uint2* __restrict__ slab,
                                                   const int* __restrict__ bstart,
                                                   unsigned* __restrict__ edges,
                                                   int* __restrict__ start) {
    __shared__ int h[BKT_SZ];
    __shared__ int sc[BKT_SZ];
    int b = blockIdx.x;
    int t = threadIdx.x;
    int base = bstart[b];
    int c = bstart[b + 1] - base;

    h[t] = 0;
    __syncthreads();
    for (int i = t; i < c; i += 512)
        atomicAdd(&h[(slab[base + i].x >> 16) & (BKT_SZ - 1)], 1);
    __syncthreads();
    int v = h[t];
    sc[t] = v;
    __syncthreads();
    for (int o = 1; o < BKT_SZ; o <<= 1) {
        int u = (t >= o) ? sc[t - o] : 0;
        __syncthreads();
        sc[t] += u;
        __syncthreads();
    }
    int excl = sc[t] - v;
    int g = (b << BKT_LOG) + t;
    if (g < N_NODES) start[g] = base + excl;
    if (b == NBKT - 1 && t == 0) start[N_NODES] = N_EDGES;
    h[t] = base + excl;
    __syncthreads();
    for (int i = t; i < c; i += 512) {
        uint2 r = slab[base + i];
        int p = atomicAdd(&h[(r.x >> 16) & (BKT_SZ - 1)], 1);
        edges[p] = (r.x & 0xFFFFu) | ((unsigned)f2bf(__uint_as_float(r.y)) << 16);
    }
}

// ---------- pull aggregation v4: bf16 table + 4B edges, 16 slots/trip ----------
template <bool RELU>
__global__ __launch_bounds__(256) void gcn_agg(const unsigned short* __restrict__ hwb,
                                               const unsigned* __restrict__ edges,
                                               const int* __restrict__ start,
                                               const float* __restrict__ b,
                                               float* __restrict__ o) {
    int n = (blockIdx.x * blockDim.x + threadIdx.x) >> 6;
    if (n >= N_NODES) return;
    int lane = threadIdx.x & 63;
    int es = lane >> 4;            // 0..3
    int f4 = (lane & 15) * 4;      // 0,4,...,60

    int i0 = start[n], i1 = start[n + 1];
    float4 acc = make_float4(0.f, 0.f, 0.f, 0.f);

    for (int base = i0; base < i1; base += 16) {
        int ia = base + es;
        int ib = base + 4 + es;
        int ic = base + 8 + es;
        int id = base + 12 + es;
        float wa = 0.f, wb = 0.f, wc = 0.f, wd = 0.f;
        float4 va = make_float4(0.f, 0.f, 0.f, 0.f);
        float4 vb = va, vc = va, vd = va;
        if (ia < i1) {
            unsigned e = edges[ia];
            wa = __uint_as_float(e & 0xFFFF0000u);
            ushort4 v = *(const ushort4*)&hwb[(long)(e & 0xFFFFu) * N_HID + f4];
            va = make_float4(bf2f(v.x), bf2f(v.y), bf2f(v.z), bf2f(v.w));
        }
        if (ib < i1) {
            unsigned e = edges[ib];
            wb = __uint_as_float(e & 0xFFFF0000u);
            ushort4 v = *(const ushort4*)&hwb[(long)(e & 0xFFFFu) * N_HID + f4];
            vb = make_float4(bf2f(v.x), bf2f(v.y), bf2f(v.z), bf2f(v.w));
        }
        if (ic < i1) {
            unsigned e = edges[ic];
            wc = __uint_as_float(e & 0xFFFF0000u);
            ushort4 v = *(const ushort4*)&hwb[(long)(e & 0xFFFFu) * N_HID + f4];
            vc = make_float4(bf2f(v.x), bf2f(v.y), bf2f(v.z), bf2f(v.w));
        }
        if (id < i1) {
            unsigned e = edges[id];
            wd = __uint_as_float(e & 0xFFFF0000u);
            ushort4 v = *(const ushort4*)&hwb[(long)(e & 0xFFFFu) * N_HID + f4];
            vd = make_float4(bf2f(v.x), bf2f(v.y), bf2f(v.z), bf2f(v.w));
        }
        fma4(acc, wa, va);
        fma4(acc, wb, vb);
        fma4(acc, wc, vc);
        fma4(acc, wd, vd);
    }

    acc.x += __shfl_xor(acc.x, 16); acc.y += __shfl_xor(acc.y, 16);
    acc.z += __shfl_xor(acc.z, 16); acc.w += __shfl_xor(acc.w, 16);
    acc.x += __shfl_xor(acc.x, 32); acc.y += __shfl_xor(acc.y, 32);
    acc.z += __shfl_xor(acc.z, 32); acc.w += __shfl_xor(acc.w, 32);

    if (es == 0) {
        float4 bias = *(const float4*)&b[f4];
        acc.x += bias.x; acc.y += bias.y; acc.z += bias.z; acc.w += bias.w;
        if (RELU) {
            acc.x = fmaxf(acc.x, 0.f); acc.y = fmaxf(acc.y, 0.f);
            acc.z = fmaxf(acc.z, 0.f); acc.w = fmaxf(acc.w, 0.f);
        }
        *(float4*)&o[(long)n * N_HID + f4] = acc;
    }
}

extern "C" void kernel_launch(void* const* d_in, const int* in_sizes, int n_in,
                              void* d_out, int out_size, void* d_ws, size_t ws_size,
                              hipStream_t stream) {
    const float* x  = (const float*)d_in[0];
    const int*   ei = (const int*)d_in[1];   // [2, E] flat: src then dst
    const float* ew = (const float*)d_in[2];
    const float* w1 = (const float*)d_in[3];
    const float* b1 = (const float*)d_in[4];
    const float* w2 = (const float*)d_in[5];
    const float* b2 = (const float*)d_in[6];
    float* out = (float*)d_out;

    const int* src = ei;
    const int* dst = ei + N_EDGES;

    // disjoint workspace (~21 MB of 256 MB)
    char* ws = (char*)d_ws;
    unsigned short* hwb = (unsigned short*)ws;                    // 6.4 MB bf16 table
    uint2* slab   = (uint2*)(ws + (size_t)7 * 1024 * 1024);       // 6.4 MB
    unsigned* edges = (unsigned*)(ws + (size_t)14 * 1024 * 1024); // 3.2 MB packed
    int*   start  = (int*)(ws + (size_t)18 * 1024 * 1024);        // 50001 ints
    int*   bstart = start + N_NODES + 3;                          // 99 ints
    int*   cnt    = bstart + NBKT + 3;                            // NB1*NBKT
    int*   cnt_t  = cnt + NB1 * NBKT;                             // NBKT*NB1
    int*   off    = cnt_t + NBKT * NB1;                           // NB1*NBKT

    dim3 blk(256);
    dim3 ngrid((N_NODES * N_HID + 255) / 256);   // 12500 (4 nodes / block)
    dim3 ggrid((N_NODES + 31) / 32);             // 1563

    // ---- build CSR: decoupled counting sort, zero global atomics ----
    binhist<<<NB1, blk, 0, stream>>>(dst, cnt, cnt_t);
    binscan<<<1, 128, 0, stream>>>(cnt_t, off, bstart);
    binscatter<<<NB1, blk, 0, stream>>>(src, dst, ew, off, slab);
    sort_bucket<<<NBKT, 512, 0, stream>>>(slab, bstart, edges, start);

    // ---- layer 1: hwb = bf16(x@w1); h = relu(agg+b1) -> d_out (f32) ----
    gemm_tile<N_FEAT><<<ggrid, blk, 0, stream>>>(x, w1, hwb);
    gcn_agg<true><<<ngrid, blk, 0, stream>>>(hwb, edges, start, b1, out);

    // ---- layer 2: hwb = bf16(h@w2); out = agg + b2 ----
    gemm_tile<N_HID><<<ggrid, blk, 0, stream>>>(out, w2, hwb);
    gcn_agg<false><<<ngrid, blk, 0, stream>>>(hwb, edges, start, b2, out);
}